// Round 1
// baseline (697.156 us; speedup 1.0000x reference)
//
#include <hip/hip_runtime.h>

#define EPS 1e-5f

constexpr int NB = 2, HQ = 272, WQ = 480, HH = 544, WH = 960, HF = 1088, WF = 1920;
constexpr int KSEL = 5000;                 // 80000/16
constexpr int NQ  = HQ * WQ;               // 130560
constexpr int NEL = NB * NQ;               // 261120
constexpr int PHA_N = NB * HF * WF;        // 4177920
constexpr int FGR_BASE = PHA_N;            // floats into d_out
constexpr int REF_BASE = PHA_N * 4;        // pha(1) + fgr(3)
constexpr int TIE_CAP = 8192;

// ---- ws layout in 4-byte units ----
constexpr int OFF_H1      = 0;              // 2*65536 u32
constexpr int OFF_H2      = 131072;         // 2*65536 u32
constexpr int OFF_META    = 262144;         // 16 ints: per image [0]=bin,[1]=C_hi,[2]=T,[3]=R
constexpr int OFF_TIECNT  = 262160;         // 2
constexpr int OFF_PCOUNT  = 262162;         // 1
constexpr int OFF_TIELIST = 262176;         // 2*TIE_CAP
constexpr int OFF_PLIST   = OFF_TIELIST + 2 * TIE_CAP;   // 278560, 10000 ints
constexpr int OFF_W       = 288576;         // 15392 floats (folded weights)
constexpr int OFF_YH      = 303968;         // NB*HH*WH*6 floats (half-res src_bgr)
constexpr int ZERO_N      = OFF_TIELIST;    // zero hists + meta + counters

// folded-weight blob offsets (floats)
constexpr int W1F = 0;      // 378*24
constexpr int B1F = 9072;   // 24
constexpr int W2F = 9096;   // 216*16
constexpr int B2F = 12552;  // 16
constexpr int W3F = 12568;  // 198*12
constexpr int B3F = 14944;  // 12
constexpr int W4F = 14956;  // 108*4
constexpr int B4F = 15388;  // 4

__global__ void zero_k(unsigned* __restrict__ p, int n) {
    int i = blockIdx.x * 256 + threadIdx.x;
    if (i < n) p[i] = 0u;
}

__global__ void fold_weights(
    const float* __restrict__ w1, const float* __restrict__ g1, const float* __restrict__ b1,
    const float* __restrict__ m1, const float* __restrict__ v1,
    const float* __restrict__ w2, const float* __restrict__ g2, const float* __restrict__ b2,
    const float* __restrict__ m2, const float* __restrict__ v2,
    const float* __restrict__ w3, const float* __restrict__ g3, const float* __restrict__ b3,
    const float* __restrict__ m3, const float* __restrict__ v3,
    const float* __restrict__ w4, const float* __restrict__ b4,
    float* __restrict__ W)
{
    __shared__ float s1[24], a1[24], s2[16], a2[16], s3[12], a3[12];
    int t = threadIdx.x;
    if (t < 24) { float s = g1[t] / sqrtf(v1[t] + EPS); s1[t] = s; a1[t] = b1[t] - m1[t] * s; }
    else if (t < 40) { int o = t - 24; float s = g2[o] / sqrtf(v2[o] + EPS); s2[o] = s; a2[o] = b2[o] - m2[o] * s; }
    else if (t < 52) { int o = t - 40; float s = g3[o] / sqrtf(v3[o] + EPS); s3[o] = s; a3[o] = b3[o] - m3[o] * s; }
    __syncthreads();
    for (int i = t; i < 9072; i += 256) W[W1F + i] = w1[i] * s1[i % 24];
    if (t < 24) W[B1F + t] = a1[t];
    for (int i = t; i < 3456; i += 256) W[W2F + i] = w2[i] * s2[i % 16];
    if (t < 16) W[B2F + t] = a2[t];
    for (int i = t; i < 2376; i += 256) W[W3F + i] = w3[i] * s3[i % 12];
    if (t < 12) W[B3F + t] = a3[t];
    for (int i = t; i < 432; i += 256) W[W4F + i] = w4[i];
    if (t < 4) W[B4F + t] = b4[t];
}

// ---------------- top-K exact selection (radix on float bits; err >= 0) ----------------
__global__ void hist_hi(const float* __restrict__ err, unsigned* __restrict__ hist) {
    int i = blockIdx.x * 256 + threadIdx.x;
    if (i >= NEL) return;
    int b = i / NQ;
    unsigned key = __float_as_uint(err[i]);
    atomicAdd(&hist[b * 65536 + (key >> 16)], 1u);
}

__global__ void find_bin(const unsigned* __restrict__ hist, int* __restrict__ meta) {
    int b = blockIdx.x;
    const unsigned* h = hist + b * 65536;
    __shared__ unsigned part[256];
    unsigned s = 0;
    for (int i = 0; i < 256; i++) s += h[threadIdx.x * 256 + i];
    part[threadIdx.x] = s;
    __syncthreads();
    if (threadIdx.x == 0) {
        unsigned cum = 0;
        int chunk = 255;
        for (; chunk >= 0; chunk--) {
            if (cum + part[chunk] >= (unsigned)KSEL) break;
            cum += part[chunk];
        }
        int bin = 0;
        for (int i = 255; i >= 0; i--) {
            unsigned c = h[chunk * 256 + i];
            if (cum + c >= (unsigned)KSEL) { bin = chunk * 256 + i; break; }
            cum += c;
        }
        meta[b * 8 + 0] = bin;
        meta[b * 8 + 1] = (int)cum;   // count strictly above bin
    }
}

__global__ void hist_lo(const float* __restrict__ err, const int* __restrict__ meta,
                        unsigned* __restrict__ hist2) {
    int i = blockIdx.x * 256 + threadIdx.x;
    if (i >= NEL) return;
    int b = i / NQ;
    unsigned key = __float_as_uint(err[i]);
    if ((int)(key >> 16) == meta[b * 8 + 0])
        atomicAdd(&hist2[b * 65536 + (key & 0xFFFFu)], 1u);
}

__global__ void find_thresh(const unsigned* __restrict__ hist2, int* __restrict__ meta) {
    int b = blockIdx.x;
    const unsigned* h = hist2 + b * 65536;
    __shared__ unsigned part[256];
    unsigned s = 0;
    for (int i = 0; i < 256; i++) s += h[threadIdx.x * 256 + i];
    part[threadIdx.x] = s;
    __syncthreads();
    if (threadIdx.x == 0) {
        unsigned cum = (unsigned)meta[b * 8 + 1];
        int chunk = 255;
        for (; chunk >= 0; chunk--) {
            if (cum + part[chunk] >= (unsigned)KSEL) break;
            cum += part[chunk];
        }
        int lo = 0; int R = 1;
        for (int i = 255; i >= 0; i--) {
            unsigned c = h[chunk * 256 + i];
            if (cum + c >= (unsigned)KSEL) { lo = chunk * 256 + i; R = KSEL - (int)cum; break; }
            cum += c;
        }
        meta[b * 8 + 2] = (int)((((unsigned)meta[b * 8 + 0]) << 16) | (unsigned)lo);  // T
        meta[b * 8 + 3] = R;                                                          // ties to take
    }
}

__global__ void tie_list_k(const float* __restrict__ err, const int* __restrict__ meta,
                           int* __restrict__ tieCnt, int* __restrict__ tieList) {
    int i = blockIdx.x * 256 + threadIdx.x;
    if (i >= NEL) return;
    int b = i / NQ;
    unsigned key = __float_as_uint(err[i]);
    if (key == (unsigned)meta[b * 8 + 2]) {
        int n = atomicAdd(&tieCnt[b], 1);
        if (n < TIE_CAP) tieList[b * TIE_CAP + n] = i - b * NQ;
    }
}

__global__ void select_k(const float* __restrict__ err, const int* __restrict__ meta,
                         int* __restrict__ plist, int* __restrict__ pcount,
                         float* __restrict__ out) {
    int i = blockIdx.x * 256 + threadIdx.x;
    if (i >= NEL) return;
    int b = i / NQ;
    unsigned key = __float_as_uint(err[i]);
    unsigned T = (unsigned)meta[b * 8 + 2];
    float r = 0.f;
    if (key > T) {                 // strictly above threshold: selected, err>0 guaranteed
        r = 1.0f;
        int n = atomicAdd(pcount, 1);
        plist[n] = i;
    }
    out[REF_BASE + i] = r;         // ties fixed up by tie_select afterwards
}

__global__ void tie_select(const int* __restrict__ meta, const int* __restrict__ tieCnt,
                           const int* __restrict__ tieList,
                           int* __restrict__ plist, int* __restrict__ pcount,
                           float* __restrict__ out) {
    int b = blockIdx.x;
    int n = tieCnt[b]; if (n > TIE_CAP) n = TIE_CAP;
    int R = meta[b * 8 + 3];
    unsigned T = (unsigned)meta[b * 8 + 2];
    float val = (T > 0u) ? 1.0f : 0.0f;   // ref = selected * (err > 0)
    for (int e = threadIdx.x; e < n; e += blockDim.x) {
        int my = tieList[b * TIE_CAP + e];
        int rank = 0;
        for (int f = 0; f < n; f++) rank += (tieList[b * TIE_CAP + f] < my) ? 1 : 0;
        if (rank < R) {           // lowest indices first (lax.top_k tie order)
            out[REF_BASE + b * NQ + my] = val;
            int q = atomicAdd(pcount, 1);
            plist[q] = b * NQ + my;
        }
    }
}

// ---------------- half-res src_bgr (antialiased bilinear downsample, 4-tap) ----------------
__global__ void yh_kernel(const float* __restrict__ src, const float* __restrict__ bgr,
                          float* __restrict__ yh) {
    int idx = blockIdx.x * 256 + threadIdx.x;
    if (idx >= NB * HH * WH) return;
    int hx = idx % WH; int t = idx / WH; int hy = t % HH; int b = t / HH;

    float wy[4]; int jy[4]; float sy = 0.f;
#pragma unroll
    for (int k = 0; k < 4; k++) {
        int j = 2 * hy - 1 + k;
        float w = (k == 0 || k == 3) ? 0.125f : 0.375f;
        if (j < 0 || j >= HF) { w = 0.f; j = 0; }
        jy[k] = j; wy[k] = w; sy += w;
    }
    float wx[4]; int jx[4]; float sx = 0.f;
#pragma unroll
    for (int k = 0; k < 4; k++) {
        int j = 2 * hx - 1 + k;
        float w = (k == 0 || k == 3) ? 0.125f : 0.375f;
        if (j < 0 || j >= WF) { w = 0.f; j = 0; }
        jx[k] = j; wx[k] = w; sx += w;
    }
    float inv = 1.f / (sy * sx);
    float acc[6] = {0.f, 0.f, 0.f, 0.f, 0.f, 0.f};
#pragma unroll
    for (int a = 0; a < 4; a++) {
#pragma unroll
        for (int c = 0; c < 4; c++) {
            float w = wy[a] * wx[c];
            int p = ((b * HF + jy[a]) * WF + jx[c]) * 3;
            acc[0] += w * src[p + 0]; acc[1] += w * src[p + 1]; acc[2] += w * src[p + 2];
            acc[3] += w * bgr[p + 0]; acc[4] += w * bgr[p + 1]; acc[5] += w * bgr[p + 2];
        }
    }
    float* Y = yh + (size_t)idx * 6;
#pragma unroll
    for (int j = 0; j < 6; j++) Y[j] = acc[j] * inv;
}

// ---------------- base 4x bilinear upsample of pha/fgr into d_out ----------------
__global__ void base_up(const float* __restrict__ pha, const float* __restrict__ fgr,
                        float* __restrict__ out) {
    int idx = blockIdx.x * 256 + threadIdx.x;
    if (idx >= PHA_N) return;
    int x = idx % WF; int t = idx / WF; int y = t % HF; int b = t / HF;
    int ky = y >> 2, ry = y & 3, kx = x >> 2, rx = x & 3;
    // r=0:(k-1,.375) r=1:(k-1,.125) r=2:(k,.875) r=3:(k,.625); edge renorm == clamp
    int qy0; float wy0;
    if (ry == 0) { qy0 = ky - 1; wy0 = 0.375f; }
    else if (ry == 1) { qy0 = ky - 1; wy0 = 0.125f; }
    else if (ry == 2) { qy0 = ky; wy0 = 0.875f; }
    else { qy0 = ky; wy0 = 0.625f; }
    int qy1 = qy0 + 1; float wy1 = 1.f - wy0;
    if (qy0 < 0) qy0 = 0; if (qy1 > HQ - 1) qy1 = HQ - 1;
    int qx0; float wx0;
    if (rx == 0) { qx0 = kx - 1; wx0 = 0.375f; }
    else if (rx == 1) { qx0 = kx - 1; wx0 = 0.125f; }
    else if (rx == 2) { qx0 = kx; wx0 = 0.875f; }
    else { qx0 = kx; wx0 = 0.625f; }
    int qx1 = qx0 + 1; float wx1 = 1.f - wx0;
    if (qx0 < 0) qx0 = 0; if (qx1 > WQ - 1) qx1 = WQ - 1;

    int rb = b * HQ;
    int p00 = (rb + qy0) * WQ + qx0, p01 = (rb + qy0) * WQ + qx1;
    int p10 = (rb + qy1) * WQ + qx0, p11 = (rb + qy1) * WQ + qx1;
    float w00 = wy0 * wx0, w01 = wy0 * wx1, w10 = wy1 * wx0, w11 = wy1 * wx1;

    out[idx] = w00 * pha[p00] + w01 * pha[p01] + w10 * pha[p10] + w11 * pha[p11];
    float* fo = out + FGR_BASE + (size_t)idx * 3;
#pragma unroll
    for (int j = 0; j < 3; j++)
        fo[j] = w00 * fgr[p00 * 3 + j] + w01 * fgr[p01 * 3 + j]
              + w10 * fgr[p10 * 3 + j] + w11 * fgr[p11 * 3 + j];
}

// ---------------- per-patch refiner CNN: 1 wave per patch ----------------
__global__ __launch_bounds__(64) void patch_kernel(
    const float* __restrict__ src, const float* __restrict__ bgr,
    const float* __restrict__ pha, const float* __restrict__ fgr,
    const float* __restrict__ hid, const float* __restrict__ yh,
    const float* __restrict__ W, const int* __restrict__ plist,
    const int* __restrict__ pcount, float* __restrict__ out)
{
    if ((int)blockIdx.x >= *pcount) return;
    int pk = plist[blockIdx.x];
    int b = pk / NQ, pos = pk % NQ;
    int iy = pos / WQ, ix = pos % WQ;
    int lane = threadIdx.x;

    __shared__ float A[2688];    // [8][8][42] conv1 input, later t2 then t3
    __shared__ float Bb[1408];   // [6][6][24] t1, later [8][8][22] conv3 input

    // Phase 0: build conv1 input = [bilinear-up(hid,pha,fgr) | yh] on 8x8 window (zero pad)
    {
        int r = lane >> 3, c = lane & 7;
        int hy = iy * 2 - 3 + r, hx = ix * 2 - 3 + c;
        float* a = &A[lane * 42];
        if (hy < 0 || hy >= HH || hx < 0 || hx >= WH) {
#pragma unroll
            for (int ch = 0; ch < 42; ch++) a[ch] = 0.f;
        } else {
            int qy0 = (hy - 1) >> 1, qy1 = qy0 + 1;
            float wy0 = (hy & 1) ? 0.75f : 0.25f, wy1 = 1.f - wy0;
            int qx0 = (hx - 1) >> 1, qx1 = qx0 + 1;
            float wx0 = (hx & 1) ? 0.75f : 0.25f, wx1 = 1.f - wx0;
            qy0 = max(qy0, 0); qy1 = min(qy1, HQ - 1);
            qx0 = max(qx0, 0); qx1 = min(qx1, WQ - 1);
            int rb = b * HQ;
            int p00 = (rb + qy0) * WQ + qx0, p01 = (rb + qy0) * WQ + qx1;
            int p10 = (rb + qy1) * WQ + qx0, p11 = (rb + qy1) * WQ + qx1;
            float w00 = wy0 * wx0, w01 = wy0 * wx1, w10 = wy1 * wx0, w11 = wy1 * wx1;
            const float4* h00 = (const float4*)(hid + (size_t)p00 * 32);
            const float4* h01 = (const float4*)(hid + (size_t)p01 * 32);
            const float4* h10 = (const float4*)(hid + (size_t)p10 * 32);
            const float4* h11 = (const float4*)(hid + (size_t)p11 * 32);
#pragma unroll
            for (int q = 0; q < 8; q++) {
                float4 v0 = h00[q], v1 = h01[q], v2 = h10[q], v3 = h11[q];
                a[q * 4 + 0] = v0.x * w00 + v1.x * w01 + v2.x * w10 + v3.x * w11;
                a[q * 4 + 1] = v0.y * w00 + v1.y * w01 + v2.y * w10 + v3.y * w11;
                a[q * 4 + 2] = v0.z * w00 + v1.z * w01 + v2.z * w10 + v3.z * w11;
                a[q * 4 + 3] = v0.w * w00 + v1.w * w01 + v2.w * w10 + v3.w * w11;
            }
            a[32] = pha[p00] * w00 + pha[p01] * w01 + pha[p10] * w10 + pha[p11] * w11;
#pragma unroll
            for (int j = 0; j < 3; j++)
                a[33 + j] = fgr[p00 * 3 + j] * w00 + fgr[p01 * 3 + j] * w01
                          + fgr[p10 * 3 + j] * w10 + fgr[p11 * 3 + j] * w11;
            const float* Y = yh + (size_t)((b * HH + hy) * WH + hx) * 6;
#pragma unroll
            for (int j = 0; j < 6; j++) a[36 + j] = Y[j];
        }
    }
    __syncthreads();

    // Phase 1: conv1 3x3x42 -> [6][6][24] (+ fused BN, ReLU) into Bb
    {
        if (lane < 36) {
            float acc[24];
            const float* bias = W + B1F;
#pragma unroll
            for (int o = 0; o < 24; o++) acc[o] = bias[o];
            int orow = lane / 6, ocol = lane % 6;
            for (int dr = 0; dr < 3; dr++)
                for (int dc = 0; dc < 3; dc++) {
                    const float* ap = &A[((orow + dr) * 8 + (ocol + dc)) * 42];
                    const float* wp = W + W1F + ((dr * 3 + dc) * 42) * 24;
                    for (int ci = 0; ci < 42; ci++) {
                        float av = ap[ci];
#pragma unroll
                        for (int o = 0; o < 24; o++) acc[o] = fmaf(av, wp[ci * 24 + o], acc[o]);
                    }
                }
            float* t1 = &Bb[lane * 24];
#pragma unroll
            for (int o = 0; o < 24; o++) t1[o] = fmaxf(acc[o], 0.f);
        }
    }
    __syncthreads();

    // Phase 2: conv2 3x3x24 -> [4][4][16] into A[0..255]
    {
        if (lane < 16) {
            float acc[16];
            const float* bias = W + B2F;
#pragma unroll
            for (int o = 0; o < 16; o++) acc[o] = bias[o];
            int orow = lane >> 2, ocol = lane & 3;
            for (int dr = 0; dr < 3; dr++)
                for (int dc = 0; dc < 3; dc++) {
                    const float* ap = &Bb[((orow + dr) * 6 + (ocol + dc)) * 24];
                    const float* wp = W + W2F + ((dr * 3 + dc) * 24) * 16;
                    for (int ci = 0; ci < 24; ci++) {
                        float av = ap[ci];
#pragma unroll
                        for (int o = 0; o < 16; o++) acc[o] = fmaf(av, wp[ci * 16 + o], acc[o]);
                    }
                }
            float* t2 = &A[lane * 16];
#pragma unroll
            for (int o = 0; o < 16; o++) t2[o] = fmaxf(acc[o], 0.f);
        }
    }
    __syncthreads();

    // Phase 2.5: conv3 input [8][8][22] = [nearest-up2(t2) | crop(src_bgr, size4 pad2)] into Bb
    {
        int r = lane >> 3, c = lane & 7;
        float* bp = &Bb[lane * 22];
        const float* t2 = &A[((r >> 1) * 4 + (c >> 1)) * 16];
#pragma unroll
        for (int ch = 0; ch < 16; ch++) bp[ch] = t2[ch];
        int fy = iy * 4 - 2 + r, fx = ix * 4 - 2 + c;
        if (fy >= 0 && fy < HF && fx >= 0 && fx < WF) {
            int p = ((b * HF + fy) * WF + fx) * 3;
            bp[16] = src[p + 0]; bp[17] = src[p + 1]; bp[18] = src[p + 2];
            bp[19] = bgr[p + 0]; bp[20] = bgr[p + 1]; bp[21] = bgr[p + 2];
        } else {
#pragma unroll
            for (int ch = 16; ch < 22; ch++) bp[ch] = 0.f;
        }
    }
    __syncthreads();

    // Phase 3: conv3 3x3x22 -> [6][6][12] into A[0..431]
    {
        if (lane < 36) {
            float acc[12];
            const float* bias = W + B3F;
#pragma unroll
            for (int o = 0; o < 12; o++) acc[o] = bias[o];
            int orow = lane / 6, ocol = lane % 6;
            for (int dr = 0; dr < 3; dr++)
                for (int dc = 0; dc < 3; dc++) {
                    const float* ap = &Bb[((orow + dr) * 8 + (ocol + dc)) * 22];
                    const float* wp = W + W3F + ((dr * 3 + dc) * 22) * 12;
                    for (int ci = 0; ci < 22; ci++) {
                        float av = ap[ci];
#pragma unroll
                        for (int o = 0; o < 12; o++) acc[o] = fmaf(av, wp[ci * 12 + o], acc[o]);
                    }
                }
            float* t3 = &A[lane * 12];
#pragma unroll
            for (int o = 0; o < 12; o++) t3[o] = fmaxf(acc[o], 0.f);
        }
    }
    __syncthreads();

    // Phase 4: conv4 3x3x12 -> [4][4][4] + b4, scatter into d_out. lane = pos*4 + och
    {
        int p = lane >> 2, o = lane & 3;
        int prow = p >> 2, pcol = p & 3;
        float acc = W[B4F + o];
        for (int dr = 0; dr < 3; dr++)
            for (int dc = 0; dc < 3; dc++) {
                const float* ap = &A[((prow + dr) * 6 + (pcol + dc)) * 12];
                const float* wp = W + W4F + ((dr * 3 + dc) * 12) * 4 + o;
#pragma unroll
                for (int ci = 0; ci < 12; ci++) acc = fmaf(ap[ci], wp[ci * 4], acc);
            }
        int y = iy * 4 + prow, x = ix * 4 + pcol;
        int fidx = (b * HF + y) * WF + x;
        if (o == 0) out[fidx] = acc;
        else out[FGR_BASE + (size_t)fidx * 3 + (o - 1)] = acc;
    }
}

extern "C" void kernel_launch(void* const* d_in, const int* in_sizes, int n_in,
                              void* d_out, int out_size, void* d_ws, size_t ws_size,
                              hipStream_t stream)
{
    const float* src = (const float*)d_in[0];
    const float* bgr = (const float*)d_in[1];
    const float* pha = (const float*)d_in[2];
    const float* fgr = (const float*)d_in[3];
    const float* err = (const float*)d_in[4];
    const float* hid = (const float*)d_in[5];
    const float* w1 = (const float*)d_in[6];
    const float* g1 = (const float*)d_in[7];
    const float* b1 = (const float*)d_in[8];
    const float* m1 = (const float*)d_in[9];
    const float* v1 = (const float*)d_in[10];
    const float* w2 = (const float*)d_in[11];
    const float* g2 = (const float*)d_in[12];
    const float* b2 = (const float*)d_in[13];
    const float* m2 = (const float*)d_in[14];
    const float* v2 = (const float*)d_in[15];
    const float* w3 = (const float*)d_in[16];
    const float* g3 = (const float*)d_in[17];
    const float* b3 = (const float*)d_in[18];
    const float* m3 = (const float*)d_in[19];
    const float* v3 = (const float*)d_in[20];
    const float* w4 = (const float*)d_in[21];
    const float* b4 = (const float*)d_in[22];

    float* out = (float*)d_out;
    unsigned* ws = (unsigned*)d_ws;
    float* wsf = (float*)d_ws;
    int* meta    = (int*)(ws + OFF_META);
    int* tieCnt  = (int*)(ws + OFF_TIECNT);
    int* pcount  = (int*)(ws + OFF_PCOUNT);
    int* tieList = (int*)(ws + OFF_TIELIST);
    int* plist   = (int*)(ws + OFF_PLIST);
    float* W  = wsf + OFF_W;
    float* yh = wsf + OFF_YH;

    zero_k<<<(ZERO_N + 255) / 256, 256, 0, stream>>>(ws, ZERO_N);
    fold_weights<<<1, 256, 0, stream>>>(w1, g1, b1, m1, v1, w2, g2, b2, m2, v2,
                                        w3, g3, b3, m3, v3, w4, b4, W);
    hist_hi<<<(NEL + 255) / 256, 256, 0, stream>>>(err, ws + OFF_H1);
    find_bin<<<NB, 256, 0, stream>>>(ws + OFF_H1, meta);
    hist_lo<<<(NEL + 255) / 256, 256, 0, stream>>>(err, meta, ws + OFF_H2);
    find_thresh<<<NB, 256, 0, stream>>>(ws + OFF_H2, meta);
    tie_list_k<<<(NEL + 255) / 256, 256, 0, stream>>>(err, meta, tieCnt, tieList);
    select_k<<<(NEL + 255) / 256, 256, 0, stream>>>(err, meta, plist, pcount, out);
    tie_select<<<NB, 256, 0, stream>>>(meta, tieCnt, tieList, plist, pcount, out);
    yh_kernel<<<(NB * HH * WH + 255) / 256, 256, 0, stream>>>(src, bgr, yh);
    base_up<<<(PHA_N + 255) / 256, 256, 0, stream>>>(pha, fgr, out);
    patch_kernel<<<NB * KSEL, 64, 0, stream>>>(src, bgr, pha, fgr, hid, yh, W, plist, pcount, out);
}

// Round 2
// 469.354 us; speedup vs baseline: 1.4854x; 1.4854x over previous
//
#include <hip/hip_runtime.h>

#define EPS 1e-5f

constexpr int NB = 2, HQ = 272, WQ = 480, HH = 544, WH = 960, HF = 1088, WF = 1920;
constexpr int KSEL = 5000;                 // 80000/16
constexpr int NQ  = HQ * WQ;               // 130560
constexpr int NEL = NB * NQ;               // 261120
constexpr int PHA_N = NB * HF * WF;        // 4177920
constexpr int FGR_BASE = PHA_N;            // floats into d_out
constexpr int REF_BASE = PHA_N * 4;        // pha(1) + fgr(3)
constexpr int TIE_CAP = 8192;

// ---- ws layout in 4-byte units ----
constexpr int OFF_H1      = 0;              // 2*65536 u32
constexpr int OFF_H2      = 131072;         // 2*65536 u32
constexpr int OFF_META    = 262144;         // 16 ints
constexpr int OFF_TIECNT  = 262160;         // 2
constexpr int OFF_PCOUNT  = 262162;         // 1
constexpr int OFF_TIELIST = 262176;         // 2*TIE_CAP
constexpr int OFF_PLIST   = OFF_TIELIST + 2 * TIE_CAP;
constexpr int OFF_W       = 288576;         // 15392 floats (folded f32 weights)
constexpr int OFF_YH      = 303968;         // NB*HH*WH*6 floats
constexpr int OFF_WP      = OFF_YH + NB * HH * WH * 6;   // 6,570,848: 32256 bf16 = 16128 dwords
constexpr int ZERO_N      = OFF_TIELIST;

// folded f32 weight blob offsets (floats)
constexpr int W1F = 0;      // [tap=9][ci=42][co=24]
constexpr int B1F = 9072;   // 24
constexpr int W2F = 9096;   // [9][24][16]
constexpr int B2F = 12552;  // 16
constexpr int W3F = 12568;  // [9][22][12]
constexpr int B3F = 14944;  // 12
constexpr int W4F = 14956;  // [9][12][4]
constexpr int B4F = 15388;  // 4

typedef short s8v __attribute__((ext_vector_type(8)));
typedef float f4v __attribute__((ext_vector_type(4)));

static __device__ __forceinline__ unsigned short f2bf(float x) {
    unsigned u = __float_as_uint(x);
    u += 0x7fffu + ((u >> 16) & 1u);
    return (unsigned short)(u >> 16);
}
static __device__ __forceinline__ unsigned pack2(float a, float b) {
    return (unsigned)f2bf(a) | ((unsigned)f2bf(b) << 16);
}

__global__ void zero_k(unsigned* __restrict__ p, int n) {
    int i = blockIdx.x * 256 + threadIdx.x;
    if (i < n) p[i] = 0u;
}

__global__ void fold_weights(
    const float* __restrict__ w1, const float* __restrict__ g1, const float* __restrict__ b1,
    const float* __restrict__ m1, const float* __restrict__ v1,
    const float* __restrict__ w2, const float* __restrict__ g2, const float* __restrict__ b2,
    const float* __restrict__ m2, const float* __restrict__ v2,
    const float* __restrict__ w3, const float* __restrict__ g3, const float* __restrict__ b3,
    const float* __restrict__ m3, const float* __restrict__ v3,
    const float* __restrict__ w4, const float* __restrict__ b4,
    float* __restrict__ W)
{
    __shared__ float s1[24], a1[24], s2[16], a2[16], s3[12], a3[12];
    int t = threadIdx.x;
    if (t < 24) { float s = g1[t] / sqrtf(v1[t] + EPS); s1[t] = s; a1[t] = b1[t] - m1[t] * s; }
    else if (t < 40) { int o = t - 24; float s = g2[o] / sqrtf(v2[o] + EPS); s2[o] = s; a2[o] = b2[o] - m2[o] * s; }
    else if (t < 52) { int o = t - 40; float s = g3[o] / sqrtf(v3[o] + EPS); s3[o] = s; a3[o] = b3[o] - m3[o] * s; }
    __syncthreads();
    for (int i = t; i < 9072; i += 256) W[W1F + i] = w1[i] * s1[i % 24];
    if (t < 24) W[B1F + t] = a1[t];
    for (int i = t; i < 3456; i += 256) W[W2F + i] = w2[i] * s2[i % 16];
    if (t < 16) W[B2F + t] = a2[t];
    for (int i = t; i < 2376; i += 256) W[W3F + i] = w3[i] * s3[i % 12];
    if (t < 12) W[B3F + t] = a3[t];
    for (int i = t; i < 432; i += 256) W[W4F + i] = w4[i];
    if (t < 4) W[B4F + t] = b4[t];
}

// Prepack folded weights into MFMA B-fragment order (bf16, zero-padded).
// frag element: idx = (frag*64 + lane)*8 + j ; lane holds n = nt*16+(lane&15),
// k = ks*32 + 8*(lane>>4) + j  (within-tap input channel).
__global__ void prepack(const float* __restrict__ Wf, unsigned short* __restrict__ P) {
    int idx = blockIdx.x * 256 + threadIdx.x;
    if (idx >= 32256) return;
    int j = idx & 7;
    int lane = (idx >> 3) & 63;
    int frag = idx >> 9;
    int li = lane & 15, g = lane >> 4;
    float val = 0.f;
    if (frag < 36) {                       // conv1: frag = (tap*2+ks)*2 + nt
        int nt = frag & 1, ks = (frag >> 1) & 1, tap = frag >> 2;
        int n = nt * 16 + li, k = ks * 32 + 8 * g + j;
        if (n < 24 && k < 42) val = Wf[W1F + (tap * 42 + k) * 24 + n];
    } else if (frag < 45) {                // conv2
        int tap = frag - 36, k = 8 * g + j;
        if (k < 24) val = Wf[W2F + (tap * 24 + k) * 16 + li];
    } else if (frag < 54) {                // conv3
        int tap = frag - 45, k = 8 * g + j;
        if (li < 12 && k < 22) val = Wf[W3F + (tap * 22 + k) * 12 + li];
    } else {                               // conv4
        int tap = frag - 54, k = 8 * g + j;
        if (li < 4 && k < 12) val = Wf[W4F + (tap * 12 + k) * 4 + li];
    }
    P[idx] = f2bf(val);
}

// ---------------- top-K exact selection ----------------
__global__ void hist_hi(const float* __restrict__ err, unsigned* __restrict__ hist) {
    int i = blockIdx.x * 256 + threadIdx.x;
    if (i >= NEL) return;
    int b = i / NQ;
    unsigned key = __float_as_uint(err[i]);
    atomicAdd(&hist[b * 65536 + (key >> 16)], 1u);
}

__global__ void find_bin(const unsigned* __restrict__ hist, int* __restrict__ meta) {
    int b = blockIdx.x, tid = threadIdx.x;
    const unsigned* h = hist + b * 65536;
    __shared__ unsigned sf[256];
    __shared__ int ssel; __shared__ unsigned scum;
    unsigned own = 0;
    for (int i = 0; i < 256; i++) own += h[tid * 256 + i];
    sf[tid] = own; __syncthreads();
    for (int off = 1; off < 256; off <<= 1) {
        unsigned v = (tid + off < 256) ? sf[tid + off] : 0u;
        __syncthreads(); sf[tid] += v; __syncthreads();
    }
    if (sf[tid] >= (unsigned)KSEL && sf[tid] - own < (unsigned)KSEL) { ssel = tid; scum = sf[tid] - own; }
    __syncthreads();
    int chunk = ssel; unsigned cum = scum;
    unsigned own2 = h[chunk * 256 + tid];
    sf[tid] = own2; __syncthreads();
    for (int off = 1; off < 256; off <<= 1) {
        unsigned v = (tid + off < 256) ? sf[tid + off] : 0u;
        __syncthreads(); sf[tid] += v; __syncthreads();
    }
    if (cum + sf[tid] >= (unsigned)KSEL && cum + sf[tid] - own2 < (unsigned)KSEL) {
        meta[b * 8 + 0] = chunk * 256 + tid;
        meta[b * 8 + 1] = (int)(cum + sf[tid] - own2);   // count strictly above bin
    }
}

__global__ void hist_lo(const float* __restrict__ err, const int* __restrict__ meta,
                        unsigned* __restrict__ hist2) {
    int i = blockIdx.x * 256 + threadIdx.x;
    if (i >= NEL) return;
    int b = i / NQ;
    unsigned key = __float_as_uint(err[i]);
    if ((int)(key >> 16) == meta[b * 8 + 0])
        atomicAdd(&hist2[b * 65536 + (key & 0xFFFFu)], 1u);
}

__global__ void find_thresh(const unsigned* __restrict__ hist2, int* __restrict__ meta) {
    int b = blockIdx.x, tid = threadIdx.x;
    const unsigned* h = hist2 + b * 65536;
    __shared__ unsigned sf[256];
    __shared__ int ssel; __shared__ unsigned scum;
    unsigned own = 0;
    for (int i = 0; i < 256; i++) own += h[tid * 256 + i];
    sf[tid] = own; __syncthreads();
    for (int off = 1; off < 256; off <<= 1) {
        unsigned v = (tid + off < 256) ? sf[tid + off] : 0u;
        __syncthreads(); sf[tid] += v; __syncthreads();
    }
    unsigned cum0 = (unsigned)meta[b * 8 + 1];
    if (cum0 + sf[tid] >= (unsigned)KSEL && cum0 + sf[tid] - own < (unsigned)KSEL) {
        ssel = tid; scum = cum0 + sf[tid] - own;
    }
    __syncthreads();
    int chunk = ssel; unsigned cum = scum;
    unsigned own2 = h[chunk * 256 + tid];
    sf[tid] = own2; __syncthreads();
    for (int off = 1; off < 256; off <<= 1) {
        unsigned v = (tid + off < 256) ? sf[tid + off] : 0u;
        __syncthreads(); sf[tid] += v; __syncthreads();
    }
    if (cum + sf[tid] >= (unsigned)KSEL && cum + sf[tid] - own2 < (unsigned)KSEL) {
        meta[b * 8 + 2] = (int)(((unsigned)meta[b * 8 + 0] << 16) | (unsigned)(chunk * 256 + tid));
        meta[b * 8 + 3] = KSEL - (int)(cum + sf[tid] - own2);   // ties to take
    }
}

__global__ void tie_list_k(const float* __restrict__ err, const int* __restrict__ meta,
                           int* __restrict__ tieCnt, int* __restrict__ tieList) {
    int i = blockIdx.x * 256 + threadIdx.x;
    if (i >= NEL) return;
    int b = i / NQ;
    unsigned key = __float_as_uint(err[i]);
    if (key == (unsigned)meta[b * 8 + 2]) {
        int n = atomicAdd(&tieCnt[b], 1);
        if (n < TIE_CAP) tieList[b * TIE_CAP + n] = i - b * NQ;
    }
}

__global__ void select_k(const float* __restrict__ err, const int* __restrict__ meta,
                         int* __restrict__ plist, int* __restrict__ pcount,
                         float* __restrict__ out) {
    int i = blockIdx.x * 256 + threadIdx.x;
    if (i >= NEL) return;
    int b = i / NQ;
    unsigned key = __float_as_uint(err[i]);
    unsigned T = (unsigned)meta[b * 8 + 2];
    float r = 0.f;
    if (key > T) {
        r = 1.0f;
        int n = atomicAdd(pcount, 1);
        plist[n] = i;
    }
    out[REF_BASE + i] = r;
}

__global__ void tie_select(const int* __restrict__ meta, const int* __restrict__ tieCnt,
                           const int* __restrict__ tieList,
                           int* __restrict__ plist, int* __restrict__ pcount,
                           float* __restrict__ out) {
    int b = blockIdx.x;
    int n = tieCnt[b]; if (n > TIE_CAP) n = TIE_CAP;
    int R = meta[b * 8 + 3];
    unsigned T = (unsigned)meta[b * 8 + 2];
    float val = (T > 0u) ? 1.0f : 0.0f;
    for (int e = threadIdx.x; e < n; e += blockDim.x) {
        int my = tieList[b * TIE_CAP + e];
        int rank = 0;
        for (int f = 0; f < n; f++) rank += (tieList[b * TIE_CAP + f] < my) ? 1 : 0;
        if (rank < R) {
            out[REF_BASE + b * NQ + my] = val;
            int q = atomicAdd(pcount, 1);
            plist[q] = b * NQ + my;
        }
    }
}

// ---------------- half-res src_bgr (antialiased 4-tap bilinear down) ----------------
__global__ void yh_kernel(const float* __restrict__ src, const float* __restrict__ bgr,
                          float* __restrict__ yh) {
    int idx = blockIdx.x * 256 + threadIdx.x;
    if (idx >= NB * HH * WH) return;
    int hx = idx % WH; int t = idx / WH; int hy = t % HH; int b = t / HH;

    float wy[4]; int jy[4]; float sy = 0.f;
#pragma unroll
    for (int k = 0; k < 4; k++) {
        int j = 2 * hy - 1 + k;
        float w = (k == 0 || k == 3) ? 0.125f : 0.375f;
        if (j < 0 || j >= HF) { w = 0.f; j = 0; }
        jy[k] = j; wy[k] = w; sy += w;
    }
    float wx[4]; int jx[4]; float sx = 0.f;
#pragma unroll
    for (int k = 0; k < 4; k++) {
        int j = 2 * hx - 1 + k;
        float w = (k == 0 || k == 3) ? 0.125f : 0.375f;
        if (j < 0 || j >= WF) { w = 0.f; j = 0; }
        jx[k] = j; wx[k] = w; sx += w;
    }
    float inv = 1.f / (sy * sx);
    float acc[6] = {0.f, 0.f, 0.f, 0.f, 0.f, 0.f};
#pragma unroll
    for (int a = 0; a < 4; a++) {
#pragma unroll
        for (int c = 0; c < 4; c++) {
            float w = wy[a] * wx[c];
            int p = ((b * HF + jy[a]) * WF + jx[c]) * 3;
            acc[0] += w * src[p + 0]; acc[1] += w * src[p + 1]; acc[2] += w * src[p + 2];
            acc[3] += w * bgr[p + 0]; acc[4] += w * bgr[p + 1]; acc[5] += w * bgr[p + 2];
        }
    }
    float* Y = yh + (size_t)idx * 6;
#pragma unroll
    for (int j = 0; j < 6; j++) Y[j] = acc[j] * inv;
}

// ---------------- base 4x bilinear upsample ----------------
__global__ void base_up(const float* __restrict__ pha, const float* __restrict__ fgr,
                        float* __restrict__ out) {
    int idx = blockIdx.x * 256 + threadIdx.x;
    if (idx >= PHA_N) return;
    int x = idx % WF; int t = idx / WF; int y = t % HF; int b = t / HF;
    int ky = y >> 2, ry = y & 3, kx = x >> 2, rx = x & 3;
    int qy0; float wy0;
    if (ry == 0) { qy0 = ky - 1; wy0 = 0.375f; }
    else if (ry == 1) { qy0 = ky - 1; wy0 = 0.125f; }
    else if (ry == 2) { qy0 = ky; wy0 = 0.875f; }
    else { qy0 = ky; wy0 = 0.625f; }
    int qy1 = qy0 + 1; float wy1 = 1.f - wy0;
    if (qy0 < 0) qy0 = 0; if (qy1 > HQ - 1) qy1 = HQ - 1;
    int qx0; float wx0;
    if (rx == 0) { qx0 = kx - 1; wx0 = 0.375f; }
    else if (rx == 1) { qx0 = kx - 1; wx0 = 0.125f; }
    else if (rx == 2) { qx0 = kx; wx0 = 0.875f; }
    else { qx0 = kx; wx0 = 0.625f; }
    int qx1 = qx0 + 1; float wx1 = 1.f - wx0;
    if (qx0 < 0) qx0 = 0; if (qx1 > WQ - 1) qx1 = WQ - 1;

    int rb = b * HQ;
    int p00 = (rb + qy0) * WQ + qx0, p01 = (rb + qy0) * WQ + qx1;
    int p10 = (rb + qy1) * WQ + qx0, p11 = (rb + qy1) * WQ + qx1;
    float w00 = wy0 * wx0, w01 = wy0 * wx1, w10 = wy1 * wx0, w11 = wy1 * wx1;

    out[idx] = w00 * pha[p00] + w01 * pha[p01] + w10 * pha[p10] + w11 * pha[p11];
    float* fo = out + FGR_BASE + (size_t)idx * 3;
#pragma unroll
    for (int j = 0; j < 3; j++)
        fo[j] = w00 * fgr[p00 * 3 + j] + w01 * fgr[p01 * 3 + j]
              + w10 * fgr[p10 * 3 + j] + w11 * fgr[p11 * 3 + j];
}

// ---------------- per-patch refiner CNN via MFMA: 1 wave per patch ----------------
// LDS: win [64][72] bf16 (conv1 input, ci 0..41 data, 42..63 zero, 64..71 bank pad)
//      aliased later as win3 [64][40] (conv3 input: 16 t2 | 6 src_bgr | zeros | pad)
//      t1s [36][40] bf16 (conv1 out, cols 24..31 zero) aliased later as t3 (conv3 out)
__global__ __launch_bounds__(64) void patch_kernel(
    const float* __restrict__ src, const float* __restrict__ bgr,
    const float* __restrict__ pha, const float* __restrict__ fgr,
    const float* __restrict__ hid, const float* __restrict__ yh,
    const float* __restrict__ Wb, const unsigned short* __restrict__ WP,
    const int* __restrict__ plist, const int* __restrict__ pcount,
    float* __restrict__ out)
{
    if ((int)blockIdx.x >= *pcount) return;
    int pk = plist[blockIdx.x];
    int b = pk / NQ, pos = pk % NQ;
    int iy = pos / WQ, ix = pos % WQ;
    int lane = threadIdx.x;
    int g = lane >> 4, li = lane & 15;

    __shared__ __align__(16) unsigned short win[64 * 72];
    __shared__ __align__(16) unsigned short t1s[36 * 40];

    const s8v* WP1v = (const s8v*)WP;          // 36 frags
    const s8v* WP2v = WP1v + 36 * 64;          // 9
    const s8v* WP3v = WP2v + 9 * 64;           // 9
    const s8v* WP4v = WP3v + 9 * 64;           // 9

    // ---- Phase 0: conv1 input window [8][8][42] -> bf16 LDS ----
    {
        int r = lane >> 3, c = lane & 7;
        int hy = iy * 2 - 3 + r, hx = ix * 2 - 3 + c;
        unsigned* wrow = (unsigned*)&win[lane * 72];
        if (hy < 0 || hy >= HH || hx < 0 || hx >= WH) {
#pragma unroll
            for (int q = 0; q < 32; q++) wrow[q] = 0u;
        } else {
            int qy0 = (hy - 1) >> 1, qy1 = qy0 + 1;
            float wy0 = (hy & 1) ? 0.75f : 0.25f, wy1 = 1.f - wy0;
            int qx0 = (hx - 1) >> 1, qx1 = qx0 + 1;
            float wx0 = (hx & 1) ? 0.75f : 0.25f, wx1 = 1.f - wx0;
            qy0 = max(qy0, 0); qy1 = min(qy1, HQ - 1);
            qx0 = max(qx0, 0); qx1 = min(qx1, WQ - 1);
            int rb = b * HQ;
            int p00 = (rb + qy0) * WQ + qx0, p01 = (rb + qy0) * WQ + qx1;
            int p10 = (rb + qy1) * WQ + qx0, p11 = (rb + qy1) * WQ + qx1;
            float w00 = wy0 * wx0, w01 = wy0 * wx1, w10 = wy1 * wx0, w11 = wy1 * wx1;
            const float4* h00 = (const float4*)(hid + (size_t)p00 * 32);
            const float4* h01 = (const float4*)(hid + (size_t)p01 * 32);
            const float4* h10 = (const float4*)(hid + (size_t)p10 * 32);
            const float4* h11 = (const float4*)(hid + (size_t)p11 * 32);
#pragma unroll
            for (int q = 0; q < 8; q++) {
                float4 v0 = h00[q], v1 = h01[q], v2 = h10[q], v3 = h11[q];
                float e0 = v0.x * w00 + v1.x * w01 + v2.x * w10 + v3.x * w11;
                float e1 = v0.y * w00 + v1.y * w01 + v2.y * w10 + v3.y * w11;
                float e2 = v0.z * w00 + v1.z * w01 + v2.z * w10 + v3.z * w11;
                float e3 = v0.w * w00 + v1.w * w01 + v2.w * w10 + v3.w * w11;
                wrow[q * 2]     = pack2(e0, e1);
                wrow[q * 2 + 1] = pack2(e2, e3);
            }
            float e32 = pha[p00] * w00 + pha[p01] * w01 + pha[p10] * w10 + pha[p11] * w11;
            float fg[3];
#pragma unroll
            for (int j = 0; j < 3; j++)
                fg[j] = fgr[p00 * 3 + j] * w00 + fgr[p01 * 3 + j] * w01
                      + fgr[p10 * 3 + j] * w10 + fgr[p11 * 3 + j] * w11;
            wrow[16] = pack2(e32, fg[0]);
            wrow[17] = pack2(fg[1], fg[2]);
            const float* Y = yh + (size_t)((b * HH + hy) * WH + hx) * 6;
            wrow[18] = pack2(Y[0], Y[1]);
            wrow[19] = pack2(Y[2], Y[3]);
            wrow[20] = pack2(Y[4], Y[5]);
#pragma unroll
            for (int q = 21; q < 32; q++) wrow[q] = 0u;
        }
    }
    __syncthreads();

    // position -> 6x6 grid cell bases (shared by conv1 & conv3)
    int p0 = li, p1 = 16 + li, p2 = (32 + li > 35) ? 35 : 32 + li;
    int pr0 = (p0 * 171) >> 10, pc0 = p0 - pr0 * 6;
    int pr1 = (p1 * 171) >> 10, pc1 = p1 - pr1 * 6;
    int pr2m = (p2 * 171) >> 10, pc2m = p2 - pr2m * 6;
    int cb0 = pr0 * 8 + pc0, cb1 = pr1 * 8 + pc1, cb2 = pr2m * 8 + pc2m;

    // ---- conv1: [36,378] x [378,24] ----
    f4v a00 = {0,0,0,0}, a01 = {0,0,0,0}, a10 = {0,0,0,0},
        a11 = {0,0,0,0}, a20 = {0,0,0,0}, a21 = {0,0,0,0};
    {
        const unsigned short* r0 = &win[cb0 * 72 + g * 8];
        const unsigned short* r1 = &win[cb1 * 72 + g * 8];
        const unsigned short* r2 = &win[cb2 * 72 + g * 8];
#pragma unroll
        for (int tap = 0; tap < 9; tap++) {
            const int dr = tap / 3, dc = tap % 3;
            const int coff = (dr * 8 + dc) * 72;
#pragma unroll
            for (int ks = 0; ks < 2; ks++) {
                s8v av0 = *(const s8v*)(r0 + coff + ks * 32);
                s8v av1 = *(const s8v*)(r1 + coff + ks * 32);
                s8v av2 = *(const s8v*)(r2 + coff + ks * 32);
                s8v bv0 = WP1v[((tap * 2 + ks) * 2 + 0) * 64 + lane];
                s8v bv1 = WP1v[((tap * 2 + ks) * 2 + 1) * 64 + lane];
                a00 = __builtin_amdgcn_mfma_f32_16x16x32_bf16(av0, bv0, a00, 0, 0, 0);
                a01 = __builtin_amdgcn_mfma_f32_16x16x32_bf16(av0, bv1, a01, 0, 0, 0);
                a10 = __builtin_amdgcn_mfma_f32_16x16x32_bf16(av1, bv0, a10, 0, 0, 0);
                a11 = __builtin_amdgcn_mfma_f32_16x16x32_bf16(av1, bv1, a11, 0, 0, 0);
                a20 = __builtin_amdgcn_mfma_f32_16x16x32_bf16(av2, bv0, a20, 0, 0, 0);
                a21 = __builtin_amdgcn_mfma_f32_16x16x32_bf16(av2, bv1, a21, 0, 0, 0);
            }
        }
    }
    // epi1 -> t1s[pos][ch], ch 24..31 get exact zeros (zero B cols + zero bias)
    {
        float b1n0 = Wb[B1F + li];
        float b1n1 = (li < 8) ? Wb[B1F + 16 + li] : 0.f;
#pragma unroll
        for (int r = 0; r < 4; r++) {
            int p = 4 * g + r;
            t1s[p * 40 + li]        = f2bf(fmaxf(a00[r] + b1n0, 0.f));
            t1s[p * 40 + 16 + li]   = f2bf(fmaxf(a01[r] + b1n1, 0.f));
            int pp = 16 + p;
            t1s[pp * 40 + li]       = f2bf(fmaxf(a10[r] + b1n0, 0.f));
            t1s[pp * 40 + 16 + li]  = f2bf(fmaxf(a11[r] + b1n1, 0.f));
            int p2r = 32 + p;
            if (p2r < 36) {
                t1s[p2r * 40 + li]      = f2bf(fmaxf(a20[r] + b1n0, 0.f));
                t1s[p2r * 40 + 16 + li] = f2bf(fmaxf(a21[r] + b1n1, 0.f));
            }
        }
    }
    __syncthreads();

    // ---- conv2: [16,216] x [216,16] ----
    f4v c2 = {0,0,0,0};
    {
        int pr = li >> 2, pc = li & 3;
#pragma unroll
        for (int tap = 0; tap < 9; tap++) {
            const int dr = tap / 3, dc = tap % 3;
            int cell = (pr + dr) * 6 + pc + dc;
            s8v av = *(const s8v*)&t1s[cell * 40 + g * 8];
            c2 = __builtin_amdgcn_mfma_f32_16x16x32_bf16(av, WP2v[tap * 64 + lane], c2, 0, 0, 0);
        }
    }
    __syncthreads();
    // epi2: nearest-up2 t2 into win3[cell][li]; then src/bgr chans + zero pads
    {
        float b2v = Wb[B2F + li];
#pragma unroll
        for (int r = 0; r < 4; r++) {
            int p = 4 * g + r;
            unsigned short hv = f2bf(fmaxf(c2[r] + b2v, 0.f));
            int r0 = (p >> 2) * 2, c0 = (p & 3) * 2;
            win[(r0 * 8 + c0) * 40 + li]       = hv;
            win[(r0 * 8 + c0 + 1) * 40 + li]   = hv;
            win[((r0 + 1) * 8 + c0) * 40 + li]     = hv;
            win[((r0 + 1) * 8 + c0 + 1) * 40 + li] = hv;
        }
        int rr = lane >> 3, cc = lane & 7;
        int fy = iy * 4 - 2 + rr, fx = ix * 4 - 2 + cc;
        unsigned* wp3 = (unsigned*)&win[lane * 40];
        if (fy >= 0 && fy < HF && fx >= 0 && fx < WF) {
            const float* sp = src + ((size_t)(b * HF + fy) * WF + fx) * 3;
            const float* bp = bgr + ((size_t)(b * HF + fy) * WF + fx) * 3;
            wp3[8]  = pack2(sp[0], sp[1]);
            wp3[9]  = pack2(sp[2], bp[0]);
            wp3[10] = pack2(bp[1], bp[2]);
        } else {
            wp3[8] = 0u; wp3[9] = 0u; wp3[10] = 0u;
        }
        wp3[11] = 0u; wp3[12] = 0u; wp3[13] = 0u; wp3[14] = 0u; wp3[15] = 0u;
        // zero t3 pad cols 16..31 (t1 data is dead now)
        for (int idx = lane; idx < 36 * 8; idx += 64) {
            int row = idx >> 3;
            ((unsigned*)t1s)[row * 20 + 8 + (idx & 7)] = 0u;
        }
    }
    __syncthreads();

    // ---- conv3: [36,198] x [198,12] ----
    f4v c30 = {0,0,0,0}, c31 = {0,0,0,0}, c32 = {0,0,0,0};
    {
        const unsigned short* r0 = &win[cb0 * 40 + g * 8];
        const unsigned short* r1 = &win[cb1 * 40 + g * 8];
        const unsigned short* r2 = &win[cb2 * 40 + g * 8];
#pragma unroll
        for (int tap = 0; tap < 9; tap++) {
            const int dr = tap / 3, dc = tap % 3;
            const int coff = (dr * 8 + dc) * 40;
            s8v bv = WP3v[tap * 64 + lane];
            c30 = __builtin_amdgcn_mfma_f32_16x16x32_bf16(*(const s8v*)(r0 + coff), bv, c30, 0, 0, 0);
            c31 = __builtin_amdgcn_mfma_f32_16x16x32_bf16(*(const s8v*)(r1 + coff), bv, c31, 0, 0, 0);
            c32 = __builtin_amdgcn_mfma_f32_16x16x32_bf16(*(const s8v*)(r2 + coff), bv, c32, 0, 0, 0);
        }
    }
    __syncthreads();
    // epi3 -> t3 (= t1s) [pos][ch], ch 12..15 exact zeros
    {
        float b3v = (li < 12) ? Wb[B3F + li] : 0.f;
#pragma unroll
        for (int r = 0; r < 4; r++) {
            int p = 4 * g + r;
            t1s[p * 40 + li]        = f2bf(fmaxf(c30[r] + b3v, 0.f));
            t1s[(16 + p) * 40 + li] = f2bf(fmaxf(c31[r] + b3v, 0.f));
            int p2r = 32 + p;
            if (p2r < 36) t1s[p2r * 40 + li] = f2bf(fmaxf(c32[r] + b3v, 0.f));
        }
    }
    __syncthreads();

    // ---- conv4: [16,108] x [108,4] (no relu) + scatter ----
    f4v c4 = {0,0,0,0};
    {
        int pr = li >> 2, pc = li & 3;
#pragma unroll
        for (int tap = 0; tap < 9; tap++) {
            const int dr = tap / 3, dc = tap % 3;
            int cell = (pr + dr) * 6 + pc + dc;
            s8v av = *(const s8v*)&t1s[cell * 40 + g * 8];
            c4 = __builtin_amdgcn_mfma_f32_16x16x32_bf16(av, WP4v[tap * 64 + lane], c4, 0, 0, 0);
        }
    }
    if (li < 4) {
        float b4v = Wb[B4F + li];
#pragma unroll
        for (int r = 0; r < 4; r++) {
            int p = 4 * g + r;
            int prow = p >> 2, pcol = p & 3;
            float v = c4[r] + b4v;
            int fidx = (b * HF + iy * 4 + prow) * WF + ix * 4 + pcol;
            if (li == 0) out[fidx] = v;
            else out[FGR_BASE + (size_t)fidx * 3 + (li - 1)] = v;
        }
    }
}

extern "C" void kernel_launch(void* const* d_in, const int* in_sizes, int n_in,
                              void* d_out, int out_size, void* d_ws, size_t ws_size,
                              hipStream_t stream)
{
    const float* src = (const float*)d_in[0];
    const float* bgr = (const float*)d_in[1];
    const float* pha = (const float*)d_in[2];
    const float* fgr = (const float*)d_in[3];
    const float* err = (const float*)d_in[4];
    const float* hid = (const float*)d_in[5];
    const float* w1 = (const float*)d_in[6];
    const float* g1 = (const float*)d_in[7];
    const float* b1 = (const float*)d_in[8];
    const float* m1 = (const float*)d_in[9];
    const float* v1 = (const float*)d_in[10];
    const float* w2 = (const float*)d_in[11];
    const float* g2 = (const float*)d_in[12];
    const float* b2 = (const float*)d_in[13];
    const float* m2 = (const float*)d_in[14];
    const float* v2 = (const float*)d_in[15];
    const float* w3 = (const float*)d_in[16];
    const float* g3 = (const float*)d_in[17];
    const float* b3 = (const float*)d_in[18];
    const float* m3 = (const float*)d_in[19];
    const float* v3 = (const float*)d_in[20];
    const float* w4 = (const float*)d_in[21];
    const float* b4 = (const float*)d_in[22];

    float* out = (float*)d_out;
    unsigned* ws = (unsigned*)d_ws;
    float* wsf = (float*)d_ws;
    int* meta    = (int*)(ws + OFF_META);
    int* tieCnt  = (int*)(ws + OFF_TIECNT);
    int* pcount  = (int*)(ws + OFF_PCOUNT);
    int* tieList = (int*)(ws + OFF_TIELIST);
    int* plist   = (int*)(ws + OFF_PLIST);
    float* W  = wsf + OFF_W;
    float* yh = wsf + OFF_YH;
    unsigned short* WP = (unsigned short*)(wsf + OFF_WP);

    zero_k<<<(ZERO_N + 255) / 256, 256, 0, stream>>>(ws, ZERO_N);
    fold_weights<<<1, 256, 0, stream>>>(w1, g1, b1, m1, v1, w2, g2, b2, m2, v2,
                                        w3, g3, b3, m3, v3, w4, b4, W);
    prepack<<<126, 256, 0, stream>>>(W, WP);
    hist_hi<<<(NEL + 255) / 256, 256, 0, stream>>>(err, ws + OFF_H1);
    find_bin<<<NB, 256, 0, stream>>>(ws + OFF_H1, meta);
    hist_lo<<<(NEL + 255) / 256, 256, 0, stream>>>(err, meta, ws + OFF_H2);
    find_thresh<<<NB, 256, 0, stream>>>(ws + OFF_H2, meta);
    tie_list_k<<<(NEL + 255) / 256, 256, 0, stream>>>(err, meta, tieCnt, tieList);
    select_k<<<(NEL + 255) / 256, 256, 0, stream>>>(err, meta, plist, pcount, out);
    tie_select<<<NB, 256, 0, stream>>>(meta, tieCnt, tieList, plist, pcount, out);
    yh_kernel<<<(NB * HH * WH + 255) / 256, 256, 0, stream>>>(src, bgr, yh);
    base_up<<<(PHA_N + 255) / 256, 256, 0, stream>>>(pha, fgr, out);
    patch_kernel<<<NB * KSEL, 64, 0, stream>>>(src, bgr, pha, fgr, hid, yh, W, WP,
                                               plist, pcount, out);
}

// Round 3
// 393.480 us; speedup vs baseline: 1.7718x; 1.1928x over previous
//
#include <hip/hip_runtime.h>

#define EPS 1e-5f

constexpr int NB = 2, HQ = 272, WQ = 480, HH = 544, WH = 960, HF = 1088, WF = 1920;
constexpr int KSEL = 5000;                 // 80000/16
constexpr int NQ  = HQ * WQ;               // 130560 = 32*4080
constexpr int NEL = NB * NQ;               // 261120
constexpr int PHA_N = NB * HF * WF;        // 4177920
constexpr int FGR_BASE = PHA_N;            // floats into d_out
constexpr int REF_BASE = PHA_N * 4;        // pha(1) + fgr(3)
constexpr int TIE_CAP = 8192;
constexpr int CHUNK = 4080;                // NQ/32

// ---- ws layout in 4-byte units ----
constexpr int OFF_H1      = 0;                    // 2*32768 (L1 hist, 15-bit bins)
constexpr int OFF_H2      = 65536;                // 2*131072 (L2 hist, 17-bit bins)
constexpr int OFF_META    = 327680;               // 16 ints
constexpr int OFF_TIECNT  = 327696;               // 2
constexpr int OFF_PCOUNT  = 327698;               // 1
constexpr int OFF_TIELIST = 327712;               // 2*TIE_CAP
constexpr int OFF_PLIST   = OFF_TIELIST + 2 * TIE_CAP;   // 344096, 10000 ints
constexpr int OFF_WB      = 354112;               // 64 floats (folded biases)
constexpr int OFF_YH      = 354176;               // NB*HH*WH*6 floats
constexpr int OFF_WP      = OFF_YH + NB * HH * WH * 6;   // 6621056: 32256 bf16
constexpr int ZERO_N      = OFF_TIELIST;          // zero hists + meta + counters

typedef short s8v __attribute__((ext_vector_type(8)));
typedef float f4v __attribute__((ext_vector_type(4)));

static __device__ __forceinline__ unsigned short f2bf(float x) {
    unsigned u = __float_as_uint(x);
    u += 0x7fffu + ((u >> 16) & 1u);
    return (unsigned short)(u >> 16);
}
static __device__ __forceinline__ unsigned pack2(float a, float b) {
    return (unsigned)f2bf(a) | ((unsigned)f2bf(b) << 16);
}

__global__ void zero_k(unsigned* __restrict__ p, int n) {
    int i = blockIdx.x * 256 + threadIdx.x;
    if (i < n) p[i] = 0u;
}

// Fold BN into weights and pack straight into MFMA B-fragment order (bf16).
// frag element: idx = (frag*64 + lane)*8 + j ; lane holds n = nt*16+(lane&15),
// k = ks*32 + 8*(lane>>4) + j. Tail threads (idx>=32256) compute folded biases.
__global__ void prepack_all(
    const float* __restrict__ w1, const float* __restrict__ g1, const float* __restrict__ b1,
    const float* __restrict__ m1, const float* __restrict__ v1,
    const float* __restrict__ w2, const float* __restrict__ g2, const float* __restrict__ b2,
    const float* __restrict__ m2, const float* __restrict__ v2,
    const float* __restrict__ w3, const float* __restrict__ g3, const float* __restrict__ b3,
    const float* __restrict__ m3, const float* __restrict__ v3,
    const float* __restrict__ w4, const float* __restrict__ b4,
    unsigned short* __restrict__ P, float* __restrict__ Wb)
{
    int idx = blockIdx.x * 256 + threadIdx.x;
    if (idx < 32256) {
        int j = idx & 7;
        int lane = (idx >> 3) & 63;
        int frag = idx >> 9;
        int li = lane & 15, g = lane >> 4;
        float val = 0.f;
        if (frag < 36) {                       // conv1: frag = (tap*2+ks)*2 + nt
            int nt = frag & 1, ks = (frag >> 1) & 1, tap = frag >> 2;
            int n = nt * 16 + li, k = ks * 32 + 8 * g + j;
            if (n < 24 && k < 42) val = w1[(tap * 42 + k) * 24 + n] * (g1[n] / sqrtf(v1[n] + EPS));
        } else if (frag < 45) {                // conv2
            int tap = frag - 36, k = 8 * g + j;
            if (k < 24) val = w2[(tap * 24 + k) * 16 + li] * (g2[li] / sqrtf(v2[li] + EPS));
        } else if (frag < 54) {                // conv3
            int tap = frag - 45, k = 8 * g + j;
            if (li < 12 && k < 22) val = w3[(tap * 22 + k) * 12 + li] * (g3[li] / sqrtf(v3[li] + EPS));
        } else {                               // conv4
            int tap = frag - 54, k = 8 * g + j;
            if (li < 4 && k < 12) val = w4[(tap * 12 + k) * 4 + li];
        }
        P[idx] = f2bf(val);
    } else {
        int o = idx - 32256;
        if (o < 24) { float s = g1[o] / sqrtf(v1[o] + EPS); Wb[o] = b1[o] - m1[o] * s; }
        else if (o < 40) { int q = o - 24; float s = g2[q] / sqrtf(v2[q] + EPS); Wb[o] = b2[q] - m2[q] * s; }
        else if (o < 52) { int q = o - 40; float s = g3[q] / sqrtf(v3[q] + EPS); Wb[o] = b3[q] - m3[q] * s; }
        else if (o < 56) Wb[o] = b4[o - 52];
    }
}

// ---------------- top-K exact selection (radix 15+17 on float bits; err >= 0) ----------------
// L1: per-block LDS-privatized 32768-bin u16 histogram (exact: chunk=4080 < 65536).
__global__ __launch_bounds__(256) void hist_l1(const float* __restrict__ err,
                                               unsigned* __restrict__ hist) {
    __shared__ unsigned lh[16384];   // 32768 u16 packed in u32
    int b = blockIdx.x >> 5, ch = blockIdx.x & 31;
    for (int i = threadIdx.x; i < 16384; i += 256) lh[i] = 0u;
    __syncthreads();
    int base = b * NQ + ch * CHUNK;
    for (int i = threadIdx.x; i < CHUNK; i += 256) {
        unsigned bin = __float_as_uint(err[base + i]) >> 17;
        atomicAdd(&lh[bin >> 1], 1u << ((bin & 1) * 16));
    }
    __syncthreads();
    unsigned* gh = hist + b * 32768;
    for (int i = threadIdx.x; i < 16384; i += 256) {
        unsigned w = lh[i];
        if (w & 0xFFFFu) atomicAdd(&gh[2 * i], w & 0xFFFFu);
        if (w >> 16)     atomicAdd(&gh[2 * i + 1], w >> 16);
    }
}

__global__ void find_bin(const unsigned* __restrict__ hist, int* __restrict__ meta) {
    int b = blockIdx.x, tid = threadIdx.x;
    const unsigned* h = hist + b * 32768;
    __shared__ unsigned sf[256];
    __shared__ int ssel; __shared__ unsigned scum;
    unsigned own = 0;
    {
        const uint4* hv = (const uint4*)(h + tid * 128);
        for (int i = 0; i < 32; i++) { uint4 v = hv[i]; own += v.x + v.y + v.z + v.w; }
    }
    sf[tid] = own; __syncthreads();
    for (int off = 1; off < 256; off <<= 1) {
        unsigned v = (tid + off < 256) ? sf[tid + off] : 0u;
        __syncthreads(); sf[tid] += v; __syncthreads();
    }
    if (sf[tid] >= (unsigned)KSEL && sf[tid] - own < (unsigned)KSEL) { ssel = tid; scum = sf[tid] - own; }
    __syncthreads();
    int chunk = ssel; unsigned cum = scum;
    unsigned own2 = (tid < 128) ? h[chunk * 128 + tid] : 0u;
    sf[tid] = own2; __syncthreads();
    for (int off = 1; off < 256; off <<= 1) {
        unsigned v = (tid + off < 256) ? sf[tid + off] : 0u;
        __syncthreads(); sf[tid] += v; __syncthreads();
    }
    if (cum + sf[tid] >= (unsigned)KSEL && cum + sf[tid] - own2 < (unsigned)KSEL) {
        meta[b * 8 + 0] = chunk * 128 + tid;            // 15-bit L1 bin
        meta[b * 8 + 1] = (int)(cum + sf[tid] - own2);  // count strictly above bin
    }
}

__global__ void hist_l2(const float* __restrict__ err, const int* __restrict__ meta,
                        unsigned* __restrict__ hist2) {
    int i = blockIdx.x * 256 + threadIdx.x;
    if (i >= NEL) return;
    int b = i / NQ;
    unsigned key = __float_as_uint(err[i]);
    if ((int)(key >> 17) == meta[b * 8 + 0])
        atomicAdd(&hist2[b * 131072 + (key & 0x1FFFFu)], 1u);
}

__global__ void find_thresh(const unsigned* __restrict__ hist2, int* __restrict__ meta) {
    int b = blockIdx.x, tid = threadIdx.x;
    const unsigned* h = hist2 + b * 131072;
    __shared__ unsigned sf[256];
    __shared__ int ssel; __shared__ unsigned scum;
    unsigned own = 0;
    {
        const uint4* hv = (const uint4*)(h + tid * 512);
        for (int i = 0; i < 128; i++) { uint4 v = hv[i]; own += v.x + v.y + v.z + v.w; }
    }
    sf[tid] = own; __syncthreads();
    for (int off = 1; off < 256; off <<= 1) {
        unsigned v = (tid + off < 256) ? sf[tid + off] : 0u;
        __syncthreads(); sf[tid] += v; __syncthreads();
    }
    unsigned cum0 = (unsigned)meta[b * 8 + 1];
    if (cum0 + sf[tid] >= (unsigned)KSEL && cum0 + sf[tid] - own < (unsigned)KSEL) {
        ssel = tid; scum = cum0 + sf[tid] - own;
    }
    __syncthreads();
    int chunk = ssel; unsigned cum = scum;
    unsigned hi = h[chunk * 512 + 2 * tid + 1], lo = h[chunk * 512 + 2 * tid];
    unsigned own2 = hi + lo;
    sf[tid] = own2; __syncthreads();
    for (int off = 1; off < 256; off <<= 1) {
        unsigned v = (tid + off < 256) ? sf[tid + off] : 0u;
        __syncthreads(); sf[tid] += v; __syncthreads();
    }
    if (cum + sf[tid] >= (unsigned)KSEL && cum + sf[tid] - own2 < (unsigned)KSEL) {
        unsigned cumo = cum + sf[tid] - own2;   // count above this thread's 2 bins
        int bl; int R;
        if (cumo + hi >= (unsigned)KSEL) { bl = 2 * tid + 1; R = KSEL - (int)cumo; }
        else { bl = 2 * tid; R = KSEL - (int)(cumo + hi); }
        unsigned low17 = (unsigned)(chunk * 512 + bl);
        meta[b * 8 + 2] = (int)(((unsigned)meta[b * 8 + 0] << 17) | low17);  // exact key T
        meta[b * 8 + 3] = R;                                                 // ties to take
    }
}

// Fused: write ref map, collect strict-above patches, collect tie candidates.
__global__ void select_tie(const float* __restrict__ err, const int* __restrict__ meta,
                           int* __restrict__ plist, int* __restrict__ pcount,
                           int* __restrict__ tieCnt, int* __restrict__ tieList,
                           float* __restrict__ out) {
    int i = blockIdx.x * 256 + threadIdx.x;
    if (i >= NEL) return;
    int b = i / NQ;
    unsigned key = __float_as_uint(err[i]);
    unsigned T = (unsigned)meta[b * 8 + 2];
    float r = 0.f;
    if (key > T) {
        r = 1.0f;
        int n = atomicAdd(pcount, 1);
        plist[n] = i;
    } else if (key == T) {
        int n = atomicAdd(&tieCnt[b], 1);
        if (n < TIE_CAP) tieList[b * TIE_CAP + n] = i - b * NQ;
    }
    out[REF_BASE + i] = r;
}

__global__ void tie_select(const int* __restrict__ meta, const int* __restrict__ tieCnt,
                           const int* __restrict__ tieList,
                           int* __restrict__ plist, int* __restrict__ pcount,
                           float* __restrict__ out) {
    int b = blockIdx.x;
    int n = tieCnt[b]; if (n > TIE_CAP) n = TIE_CAP;
    int R = meta[b * 8 + 3];
    unsigned T = (unsigned)meta[b * 8 + 2];
    float val = (T > 0u) ? 1.0f : 0.0f;   // ref = selected * (err > 0)
    for (int e = threadIdx.x; e < n; e += blockDim.x) {
        int my = tieList[b * TIE_CAP + e];
        int rank = 0;
        for (int f = 0; f < n; f++) rank += (tieList[b * TIE_CAP + f] < my) ? 1 : 0;
        if (rank < R) {           // lowest indices first (lax.top_k tie order)
            out[REF_BASE + b * NQ + my] = val;
            int q = atomicAdd(pcount, 1);
            plist[q] = b * NQ + my;
        }
    }
}

// ---------------- half-res src_bgr (antialiased 4-tap bilinear down) ----------------
__global__ void yh_kernel(const float* __restrict__ src, const float* __restrict__ bgr,
                          float* __restrict__ yh) {
    int idx = blockIdx.x * 256 + threadIdx.x;
    if (idx >= NB * HH * WH) return;
    int hx = idx % WH; int t = idx / WH; int hy = t % HH; int b = t / HH;

    float wy[4]; int jy[4]; float sy = 0.f;
#pragma unroll
    for (int k = 0; k < 4; k++) {
        int j = 2 * hy - 1 + k;
        float w = (k == 0 || k == 3) ? 0.125f : 0.375f;
        if (j < 0 || j >= HF) { w = 0.f; j = 0; }
        jy[k] = j; wy[k] = w; sy += w;
    }
    float wx[4]; int jx[4]; float sx = 0.f;
#pragma unroll
    for (int k = 0; k < 4; k++) {
        int j = 2 * hx - 1 + k;
        float w = (k == 0 || k == 3) ? 0.125f : 0.375f;
        if (j < 0 || j >= WF) { w = 0.f; j = 0; }
        jx[k] = j; wx[k] = w; sx += w;
    }
    float inv = 1.f / (sy * sx);
    float acc[6] = {0.f, 0.f, 0.f, 0.f, 0.f, 0.f};
#pragma unroll
    for (int a = 0; a < 4; a++) {
#pragma unroll
        for (int c = 0; c < 4; c++) {
            float w = wy[a] * wx[c];
            int p = ((b * HF + jy[a]) * WF + jx[c]) * 3;
            acc[0] += w * src[p + 0]; acc[1] += w * src[p + 1]; acc[2] += w * src[p + 2];
            acc[3] += w * bgr[p + 0]; acc[4] += w * bgr[p + 1]; acc[5] += w * bgr[p + 2];
        }
    }
    float* Y = yh + (size_t)idx * 6;
#pragma unroll
    for (int j = 0; j < 6; j++) Y[j] = acc[j] * inv;
}

// ---------------- base 4x bilinear upsample ----------------
__global__ void base_up(const float* __restrict__ pha, const float* __restrict__ fgr,
                        float* __restrict__ out) {
    int idx = blockIdx.x * 256 + threadIdx.x;
    if (idx >= PHA_N) return;
    int x = idx % WF; int t = idx / WF; int y = t % HF; int b = t / HF;
    int ky = y >> 2, ry = y & 3, kx = x >> 2, rx = x & 3;
    int qy0; float wy0;
    if (ry == 0) { qy0 = ky - 1; wy0 = 0.375f; }
    else if (ry == 1) { qy0 = ky - 1; wy0 = 0.125f; }
    else if (ry == 2) { qy0 = ky; wy0 = 0.875f; }
    else { qy0 = ky; wy0 = 0.625f; }
    int qy1 = qy0 + 1; float wy1 = 1.f - wy0;
    if (qy0 < 0) qy0 = 0; if (qy1 > HQ - 1) qy1 = HQ - 1;
    int qx0; float wx0;
    if (rx == 0) { qx0 = kx - 1; wx0 = 0.375f; }
    else if (rx == 1) { qx0 = kx - 1; wx0 = 0.125f; }
    else if (rx == 2) { qx0 = kx; wx0 = 0.875f; }
    else { qx0 = kx; wx0 = 0.625f; }
    int qx1 = qx0 + 1; float wx1 = 1.f - wx0;
    if (qx0 < 0) qx0 = 0; if (qx1 > WQ - 1) qx1 = WQ - 1;

    int rb = b * HQ;
    int p00 = (rb + qy0) * WQ + qx0, p01 = (rb + qy0) * WQ + qx1;
    int p10 = (rb + qy1) * WQ + qx0, p11 = (rb + qy1) * WQ + qx1;
    float w00 = wy0 * wx0, w01 = wy0 * wx1, w10 = wy1 * wx0, w11 = wy1 * wx1;

    out[idx] = w00 * pha[p00] + w01 * pha[p01] + w10 * pha[p10] + w11 * pha[p11];
    float* fo = out + FGR_BASE + (size_t)idx * 3;
#pragma unroll
    for (int j = 0; j < 3; j++)
        fo[j] = w00 * fgr[p00 * 3 + j] + w01 * fgr[p01 * 3 + j]
              + w10 * fgr[p10 * 3 + j] + w11 * fgr[p11 * 3 + j];
}

// ---------------- per-patch refiner CNN via MFMA: 1 wave per patch ----------------
__global__ __launch_bounds__(64) void patch_kernel(
    const float* __restrict__ src, const float* __restrict__ bgr,
    const float* __restrict__ pha, const float* __restrict__ fgr,
    const float* __restrict__ hid, const float* __restrict__ yh,
    const float* __restrict__ Wb, const unsigned short* __restrict__ WP,
    const int* __restrict__ plist, const int* __restrict__ pcount,
    float* __restrict__ out)
{
    if ((int)blockIdx.x >= *pcount) return;
    int pk = plist[blockIdx.x];
    int b = pk / NQ, pos = pk % NQ;
    int iy = pos / WQ, ix = pos % WQ;
    int lane = threadIdx.x;
    int g = lane >> 4, li = lane & 15;

    __shared__ __align__(16) unsigned short win[64 * 72];
    __shared__ __align__(16) unsigned short t1s[36 * 40];

    const s8v* WP1v = (const s8v*)WP;          // 36 frags
    const s8v* WP2v = WP1v + 36 * 64;          // 9
    const s8v* WP3v = WP2v + 9 * 64;           // 9
    const s8v* WP4v = WP3v + 9 * 64;           // 9

    // ---- Phase 0: conv1 input window [8][8][42] -> bf16 LDS ----
    {
        int r = lane >> 3, c = lane & 7;
        int hy = iy * 2 - 3 + r, hx = ix * 2 - 3 + c;
        unsigned* wrow = (unsigned*)&win[lane * 72];
        if (hy < 0 || hy >= HH || hx < 0 || hx >= WH) {
#pragma unroll
            for (int q = 0; q < 32; q++) wrow[q] = 0u;
        } else {
            int qy0 = (hy - 1) >> 1, qy1 = qy0 + 1;
            float wy0 = (hy & 1) ? 0.75f : 0.25f, wy1 = 1.f - wy0;
            int qx0 = (hx - 1) >> 1, qx1 = qx0 + 1;
            float wx0 = (hx & 1) ? 0.75f : 0.25f, wx1 = 1.f - wx0;
            qy0 = max(qy0, 0); qy1 = min(qy1, HQ - 1);
            qx0 = max(qx0, 0); qx1 = min(qx1, WQ - 1);
            int rb = b * HQ;
            int p00 = (rb + qy0) * WQ + qx0, p01 = (rb + qy0) * WQ + qx1;
            int p10 = (rb + qy1) * WQ + qx0, p11 = (rb + qy1) * WQ + qx1;
            float w00 = wy0 * wx0, w01 = wy0 * wx1, w10 = wy1 * wx0, w11 = wy1 * wx1;
            const float4* h00 = (const float4*)(hid + (size_t)p00 * 32);
            const float4* h01 = (const float4*)(hid + (size_t)p01 * 32);
            const float4* h10 = (const float4*)(hid + (size_t)p10 * 32);
            const float4* h11 = (const float4*)(hid + (size_t)p11 * 32);
#pragma unroll
            for (int q = 0; q < 8; q++) {
                float4 v0 = h00[q], v1 = h01[q], v2 = h10[q], v3 = h11[q];
                float e0 = v0.x * w00 + v1.x * w01 + v2.x * w10 + v3.x * w11;
                float e1 = v0.y * w00 + v1.y * w01 + v2.y * w10 + v3.y * w11;
                float e2 = v0.z * w00 + v1.z * w01 + v2.z * w10 + v3.z * w11;
                float e3 = v0.w * w00 + v1.w * w01 + v2.w * w10 + v3.w * w11;
                wrow[q * 2]     = pack2(e0, e1);
                wrow[q * 2 + 1] = pack2(e2, e3);
            }
            float e32 = pha[p00] * w00 + pha[p01] * w01 + pha[p10] * w10 + pha[p11] * w11;
            float fg[3];
#pragma unroll
            for (int j = 0; j < 3; j++)
                fg[j] = fgr[p00 * 3 + j] * w00 + fgr[p01 * 3 + j] * w01
                      + fgr[p10 * 3 + j] * w10 + fgr[p11 * 3 + j] * w11;
            wrow[16] = pack2(e32, fg[0]);
            wrow[17] = pack2(fg[1], fg[2]);
            const float* Y = yh + (size_t)((b * HH + hy) * WH + hx) * 6;
            wrow[18] = pack2(Y[0], Y[1]);
            wrow[19] = pack2(Y[2], Y[3]);
            wrow[20] = pack2(Y[4], Y[5]);
#pragma unroll
            for (int q = 21; q < 32; q++) wrow[q] = 0u;
        }
    }
    __syncthreads();

    // position -> 6x6 grid cell bases (shared by conv1 & conv3)
    int p0 = li, p1 = 16 + li, p2 = (32 + li > 35) ? 35 : 32 + li;
    int pr0 = (p0 * 171) >> 10, pc0 = p0 - pr0 * 6;
    int pr1 = (p1 * 171) >> 10, pc1 = p1 - pr1 * 6;
    int pr2m = (p2 * 171) >> 10, pc2m = p2 - pr2m * 6;
    int cb0 = pr0 * 8 + pc0, cb1 = pr1 * 8 + pc1, cb2 = pr2m * 8 + pc2m;

    // ---- conv1: [36,378] x [378,24] ----
    f4v a00 = {0,0,0,0}, a01 = {0,0,0,0}, a10 = {0,0,0,0},
        a11 = {0,0,0,0}, a20 = {0,0,0,0}, a21 = {0,0,0,0};
    {
        const unsigned short* r0 = &win[cb0 * 72 + g * 8];
        const unsigned short* r1 = &win[cb1 * 72 + g * 8];
        const unsigned short* r2 = &win[cb2 * 72 + g * 8];
#pragma unroll
        for (int tap = 0; tap < 9; tap++) {
            const int dr = tap / 3, dc = tap % 3;
            const int coff = (dr * 8 + dc) * 72;
#pragma unroll
            for (int ks = 0; ks < 2; ks++) {
                s8v av0 = *(const s8v*)(r0 + coff + ks * 32);
                s8v av1 = *(const s8v*)(r1 + coff + ks * 32);
                s8v av2 = *(const s8v*)(r2 + coff + ks * 32);
                s8v bv0 = WP1v[((tap * 2 + ks) * 2 + 0) * 64 + lane];
                s8v bv1 = WP1v[((tap * 2 + ks) * 2 + 1) * 64 + lane];
                a00 = __builtin_amdgcn_mfma_f32_16x16x32_bf16(av0, bv0, a00, 0, 0, 0);
                a01 = __builtin_amdgcn_mfma_f32_16x16x32_bf16(av0, bv1, a01, 0, 0, 0);
                a10 = __builtin_amdgcn_mfma_f32_16x16x32_bf16(av1, bv0, a10, 0, 0, 0);
                a11 = __builtin_amdgcn_mfma_f32_16x16x32_bf16(av1, bv1, a11, 0, 0, 0);
                a20 = __builtin_amdgcn_mfma_f32_16x16x32_bf16(av2, bv0, a20, 0, 0, 0);
                a21 = __builtin_amdgcn_mfma_f32_16x16x32_bf16(av2, bv1, a21, 0, 0, 0);
            }
        }
    }
    // epi1 -> t1s[pos][ch], ch 24..31 exact zeros (zero B cols + zero bias)
    {
        float b1n0 = Wb[li];
        float b1n1 = (li < 8) ? Wb[16 + li] : 0.f;
#pragma unroll
        for (int r = 0; r < 4; r++) {
            int p = 4 * g + r;
            t1s[p * 40 + li]        = f2bf(fmaxf(a00[r] + b1n0, 0.f));
            t1s[p * 40 + 16 + li]   = f2bf(fmaxf(a01[r] + b1n1, 0.f));
            int pp = 16 + p;
            t1s[pp * 40 + li]       = f2bf(fmaxf(a10[r] + b1n0, 0.f));
            t1s[pp * 40 + 16 + li]  = f2bf(fmaxf(a11[r] + b1n1, 0.f));
            int p2r = 32 + p;
            if (p2r < 36) {
                t1s[p2r * 40 + li]      = f2bf(fmaxf(a20[r] + b1n0, 0.f));
                t1s[p2r * 40 + 16 + li] = f2bf(fmaxf(a21[r] + b1n1, 0.f));
            }
        }
    }
    __syncthreads();

    // ---- conv2: [16,216] x [216,16] ----
    f4v c2 = {0,0,0,0};
    {
        int pr = li >> 2, pc = li & 3;
#pragma unroll
        for (int tap = 0; tap < 9; tap++) {
            const int dr = tap / 3, dc = tap % 3;
            int cell = (pr + dr) * 6 + pc + dc;
            s8v av = *(const s8v*)&t1s[cell * 40 + g * 8];
            c2 = __builtin_amdgcn_mfma_f32_16x16x32_bf16(av, WP2v[tap * 64 + lane], c2, 0, 0, 0);
        }
    }
    __syncthreads();
    // epi2: nearest-up2 t2 into win3[cell][li]; then src/bgr chans + zero pads
    {
        float b2v = Wb[24 + li];
#pragma unroll
        for (int r = 0; r < 4; r++) {
            int p = 4 * g + r;
            unsigned short hv = f2bf(fmaxf(c2[r] + b2v, 0.f));
            int r0 = (p >> 2) * 2, c0 = (p & 3) * 2;
            win[(r0 * 8 + c0) * 40 + li]       = hv;
            win[(r0 * 8 + c0 + 1) * 40 + li]   = hv;
            win[((r0 + 1) * 8 + c0) * 40 + li]     = hv;
            win[((r0 + 1) * 8 + c0 + 1) * 40 + li] = hv;
        }
        int rr = lane >> 3, cc = lane & 7;
        int fy = iy * 4 - 2 + rr, fx = ix * 4 - 2 + cc;
        unsigned* wp3 = (unsigned*)&win[lane * 40];
        if (fy >= 0 && fy < HF && fx >= 0 && fx < WF) {
            const float* sp = src + ((size_t)(b * HF + fy) * WF + fx) * 3;
            const float* bp = bgr + ((size_t)(b * HF + fy) * WF + fx) * 3;
            wp3[8]  = pack2(sp[0], sp[1]);
            wp3[9]  = pack2(sp[2], bp[0]);
            wp3[10] = pack2(bp[1], bp[2]);
        } else {
            wp3[8] = 0u; wp3[9] = 0u; wp3[10] = 0u;
        }
        wp3[11] = 0u; wp3[12] = 0u; wp3[13] = 0u; wp3[14] = 0u; wp3[15] = 0u;
        // zero t3 pad cols 16..31 (t1 data is dead now)
        for (int idx = lane; idx < 36 * 8; idx += 64) {
            int row = idx >> 3;
            ((unsigned*)t1s)[row * 20 + 8 + (idx & 7)] = 0u;
        }
    }
    __syncthreads();

    // ---- conv3: [36,198] x [198,12] ----
    f4v c30 = {0,0,0,0}, c31 = {0,0,0,0}, c32 = {0,0,0,0};
    {
        const unsigned short* r0 = &win[cb0 * 40 + g * 8];
        const unsigned short* r1 = &win[cb1 * 40 + g * 8];
        const unsigned short* r2 = &win[cb2 * 40 + g * 8];
#pragma unroll
        for (int tap = 0; tap < 9; tap++) {
            const int dr = tap / 3, dc = tap % 3;
            const int coff = (dr * 8 + dc) * 40;
            s8v bv = WP3v[tap * 64 + lane];
            c30 = __builtin_amdgcn_mfma_f32_16x16x32_bf16(*(const s8v*)(r0 + coff), bv, c30, 0, 0, 0);
            c31 = __builtin_amdgcn_mfma_f32_16x16x32_bf16(*(const s8v*)(r1 + coff), bv, c31, 0, 0, 0);
            c32 = __builtin_amdgcn_mfma_f32_16x16x32_bf16(*(const s8v*)(r2 + coff), bv, c32, 0, 0, 0);
        }
    }
    __syncthreads();
    // epi3 -> t3 (= t1s) [pos][ch], ch 12..15 exact zeros
    {
        float b3v = (li < 12) ? Wb[40 + li] : 0.f;
#pragma unroll
        for (int r = 0; r < 4; r++) {
            int p = 4 * g + r;
            t1s[p * 40 + li]        = f2bf(fmaxf(c30[r] + b3v, 0.f));
            t1s[(16 + p) * 40 + li] = f2bf(fmaxf(c31[r] + b3v, 0.f));
            int p2r = 32 + p;
            if (p2r < 36) t1s[p2r * 40 + li] = f2bf(fmaxf(c32[r] + b3v, 0.f));
        }
    }
    __syncthreads();

    // ---- conv4: [16,108] x [108,4] (no relu) + scatter ----
    f4v c4 = {0,0,0,0};
    {
        int pr = li >> 2, pc = li & 3;
#pragma unroll
        for (int tap = 0; tap < 9; tap++) {
            const int dr = tap / 3, dc = tap % 3;
            int cell = (pr + dr) * 6 + pc + dc;
            s8v av = *(const s8v*)&t1s[cell * 40 + g * 8];
            c4 = __builtin_amdgcn_mfma_f32_16x16x32_bf16(av, WP4v[tap * 64 + lane], c4, 0, 0, 0);
        }
    }
    if (li < 4) {
        float b4v = Wb[52 + li];
#pragma unroll
        for (int r = 0; r < 4; r++) {
            int p = 4 * g + r;
            int prow = p >> 2, pcol = p & 3;
            float v = c4[r] + b4v;
            int fidx = (b * HF + iy * 4 + prow) * WF + ix * 4 + pcol;
            if (li == 0) out[fidx] = v;
            else out[FGR_BASE + (size_t)fidx * 3 + (li - 1)] = v;
        }
    }
}

extern "C" void kernel_launch(void* const* d_in, const int* in_sizes, int n_in,
                              void* d_out, int out_size, void* d_ws, size_t ws_size,
                              hipStream_t stream)
{
    const float* src = (const float*)d_in[0];
    const float* bgr = (const float*)d_in[1];
    const float* pha = (const float*)d_in[2];
    const float* fgr = (const float*)d_in[3];
    const float* err = (const float*)d_in[4];
    const float* hid = (const float*)d_in[5];
    const float* w1 = (const float*)d_in[6];
    const float* g1 = (const float*)d_in[7];
    const float* b1 = (const float*)d_in[8];
    const float* m1 = (const float*)d_in[9];
    const float* v1 = (const float*)d_in[10];
    const float* w2 = (const float*)d_in[11];
    const float* g2 = (const float*)d_in[12];
    const float* b2 = (const float*)d_in[13];
    const float* m2 = (const float*)d_in[14];
    const float* v2 = (const float*)d_in[15];
    const float* w3 = (const float*)d_in[16];
    const float* g3 = (const float*)d_in[17];
    const float* b3 = (const float*)d_in[18];
    const float* m3 = (const float*)d_in[19];
    const float* v3 = (const float*)d_in[20];
    const float* w4 = (const float*)d_in[21];
    const float* b4 = (const float*)d_in[22];

    float* out = (float*)d_out;
    unsigned* ws = (unsigned*)d_ws;
    float* wsf = (float*)d_ws;
    int* meta    = (int*)(ws + OFF_META);
    int* tieCnt  = (int*)(ws + OFF_TIECNT);
    int* pcount  = (int*)(ws + OFF_PCOUNT);
    int* tieList = (int*)(ws + OFF_TIELIST);
    int* plist   = (int*)(ws + OFF_PLIST);
    float* Wb = wsf + OFF_WB;
    float* yh = wsf + OFF_YH;
    unsigned short* WP = (unsigned short*)(wsf + OFF_WP);

    zero_k<<<(ZERO_N + 255) / 256, 256, 0, stream>>>(ws, ZERO_N);
    prepack_all<<<127, 256, 0, stream>>>(w1, g1, b1, m1, v1, w2, g2, b2, m2, v2,
                                         w3, g3, b3, m3, v3, w4, b4, WP, Wb);
    hist_l1<<<64, 256, 0, stream>>>(err, ws + OFF_H1);
    find_bin<<<NB, 256, 0, stream>>>(ws + OFF_H1, meta);
    hist_l2<<<(NEL + 255) / 256, 256, 0, stream>>>(err, meta, ws + OFF_H2);
    find_thresh<<<NB, 256, 0, stream>>>(ws + OFF_H2, meta);
    select_tie<<<(NEL + 255) / 256, 256, 0, stream>>>(err, meta, plist, pcount,
                                                      tieCnt, tieList, out);
    tie_select<<<NB, 256, 0, stream>>>(meta, tieCnt, tieList, plist, pcount, out);
    yh_kernel<<<(NB * HH * WH + 255) / 256, 256, 0, stream>>>(src, bgr, yh);
    base_up<<<(PHA_N + 255) / 256, 256, 0, stream>>>(pha, fgr, out);
    patch_kernel<<<NB * KSEL, 64, 0, stream>>>(src, bgr, pha, fgr, hid, yh, Wb, WP,
                                               plist, pcount, out);
}